// Round 4
// baseline (300.766 us; speedup 1.0000x reference)
//
#include <hip/hip_runtime.h>
#include <hip/hip_bf16.h>
#include <cstdint>

typedef __bf16 bf16_t;
typedef __bf16 bf16x8 __attribute__((ext_vector_type(8)));
typedef __bf16 bf16x4 __attribute__((ext_vector_type(4)));
typedef float f32x4 __attribute__((ext_vector_type(4)));

static constexpr int B = 16, N = 1024, D = 768;
static constexpr float SCALE = 0.03608439182435161f; // 768^-0.5

// async global->LDS, 16B per lane, wave-uniform LDS base + lane*16
#define ASYNC_COPY16(gptr, lptr)                                                          \
  __builtin_amdgcn_global_load_lds((const __attribute__((address_space(1))) void*)(gptr), \
                                   (__attribute__((address_space(3))) void*)(lptr), 16, 0, 0)

// ---------------- helpers ----------------
__device__ __forceinline__ float wave_red_max(float v) {
#pragma unroll
  for (int o = 32; o > 0; o >>= 1) v = fmaxf(v, __shfl_down(v, o, 64));
  return v;
}
__device__ __forceinline__ float wave_red_sum(float v) {
#pragma unroll
  for (int o = 32; o > 0; o >>= 1) v += __shfl_down(v, o, 64);
  return v;
}
__device__ __forceinline__ float block_max(float v, float* sm) {
  v = wave_red_max(v);
  int lane = threadIdx.x & 63, w = threadIdx.x >> 6;
  if (lane == 0) sm[w] = v;
  __syncthreads();
  return fmaxf(fmaxf(sm[0], sm[1]), fmaxf(sm[2], sm[3]));
}
__device__ __forceinline__ float block_sum(float v, float* sm) {
  v = wave_red_sum(v);
  int lane = threadIdx.x & 63, w = threadIdx.x >> 6;
  if (lane == 0) sm[w] = v;
  __syncthreads();
  return sm[0] + sm[1] + sm[2] + sm[3];
}

// ---------------- cast fp32 -> bf16 (4 elems / thread) ----------------
__global__ __launch_bounds__(256) void cast_f32_bf16_4(const float4* __restrict__ in,
                                                       bf16x4* __restrict__ out, int n4) {
  int i = blockIdx.x * 256 + threadIdx.x;
  if (i < n4) {
    float4 v = in[i];
    bf16x4 o;
    o.x = (bf16_t)v.x; o.y = (bf16_t)v.y; o.z = (bf16_t)v.z; o.w = (bf16_t)v.w;
    out[i] = o;
  }
}

// ---------------- fused cast+transpose: y f32 [B][N][D] -> yb bf16 [B][N][D] + yT bf16 [B][D][N]
__global__ __launch_bounds__(256) void cast_transpose_y(const float* __restrict__ y,
                                                        bf16_t* __restrict__ yb,
                                                        bf16_t* __restrict__ yT) {
  __shared__ bf16_t t[32][33];
  int b = blockIdx.z;
  int d0 = blockIdx.x * 32;
  int n0 = blockIdx.y * 32;
  int tx = threadIdx.x & 31;
  int ty = threadIdx.x >> 5; // 0..7
  const float* src = y + (size_t)b * N * D;
  bf16_t* dstN = yb + (size_t)b * N * D;
  bf16_t* dstT = yT + (size_t)b * N * D;
#pragma unroll
  for (int r = 0; r < 4; r++) {
    int n = n0 + ty + r * 8;
    float v = src[(size_t)n * D + d0 + tx];
    bf16_t h = (bf16_t)v;
    t[ty + r * 8][tx] = h;
    dstN[(size_t)n * D + d0 + tx] = h;
  }
  __syncthreads();
#pragma unroll
  for (int r = 0; r < 4; r++) {
    int d = d0 + ty + r * 8;
    dstT[(size_t)d * N + n0 + tx] = t[tx][ty + r * 8];
  }
}

// ---------------- positional softmax: pos[p][n] ----------------
__global__ __launch_bounds__(256) void pos_softmax_k(const float* __restrict__ coords,
                                                     const float* __restrict__ pemb,
                                                     float* __restrict__ pos) {
  __shared__ float sm1[4], sm2[4];
  int p = blockIdx.x;
  int tid = threadIdx.x;
  float e[6];
#pragma unroll
  for (int k = 0; k < 6; k++) e[k] = pemb[p * 6 + k];
  float v[4];
#pragma unroll
  for (int i = 0; i < 4; i++) {
    int n = tid + i * 256;
    const float* c = coords + ((size_t)p * N + n) * 6;
    float s = 0.f;
#pragma unroll
    for (int k = 0; k < 6; k++) s += c[k] * e[k];
    v[i] = s;
  }
  float m = block_max(fmaxf(fmaxf(v[0], v[1]), fmaxf(v[2], v[3])), sm1);
  float ex[4], ls = 0.f;
#pragma unroll
  for (int i = 0; i < 4; i++) { ex[i] = __expf(v[i] - m); ls += ex[i]; }
  float sum = block_sum(ls, sm2);
  float inv = 1.f / sum;
#pragma unroll
  for (int i = 0; i < 4; i++) pos[(size_t)p * N + tid + i * 256] = ex[i] * inv;
}

// ---------------- softmax + gate + entropy; writes attn bf16 in place ----------------
__global__ __launch_bounds__(256) void attn_entropy_k(float* __restrict__ S,
                                                      const float* __restrict__ pos,
                                                      const float* __restrict__ gating,
                                                      const float* __restrict__ temp,
                                                      float* __restrict__ hmap) {
  __shared__ float sm1[4], sm2[4], sm3[4];
  size_t row = blockIdx.x; // 0 .. B*N-1
  int q = (int)(row & (size_t)(N - 1));
  int tid = threadIdx.x;
  float* Srow = S + row * N;
  float g = 1.f / (1.f + __expf(-gating[0]));
  float s[4];
#pragma unroll
  for (int i = 0; i < 4; i++) s[i] = Srow[tid + i * 256];
  float m = block_max(fmaxf(fmaxf(s[0], s[1]), fmaxf(s[2], s[3])), sm1);
  float e[4], ls = 0.f;
#pragma unroll
  for (int i = 0; i < 4; i++) { e[i] = __expf(s[i] - m); ls += e[i]; }
  float sum = block_sum(ls, sm2);
  float inv = 1.f / sum;
  const float* prow = pos + (size_t)q * N;
  float a[4], ent = 0.f;
#pragma unroll
  for (int i = 0; i < 4; i++) {
    float patch = e[i] * inv;
    float ps = prow[tid + i * 256];
    a[i] = (1.f - g) * patch + g * ps;
    ent += -a[i] * __logf(a[i] + 1e-8f);
  }
  float E = block_sum(ent, sm3);
  __syncthreads(); // all reads of Srow complete before bf16 overwrite
  bf16_t* arow = (bf16_t*)Srow; // in-place: bf16 row lives in first 2 KB of the 4 KB fp32 slot
#pragma unroll
  for (int i = 0; i < 4; i++) arow[tid + i * 256] = (bf16_t)a[i];
  // hmap = 2*(1 - sigmoid(z)) = 2/(1+exp(z)),  z = temp*E
  if (tid == 0) hmap[row] = 2.f / (1.f + __expf(temp[0] * E));
}

// ---------------- NT GEMM: 256x256 tile, BK=64, 8 waves, 8-phase counted-vmcnt ----
// C[M][Nc] = A[M][K] * B[Nc][K]^T * scale.   REQUIRES: K % 128 == 0 (nk even).
// 8 waves in 2(M)x4(N); each wave owns 128x64 (acc[8][4] of 16x16 frags).
// LDS ring: 2 K-tile buffers x (A 256x64 + B 256x64) bf16 = 2 x 64KB = 128KB.
//
// R4: SINGLE barrier per phase. Each wave's MFMA depends on its own frag ds_reads,
// so the compiler's lgkmcnt-before-MFMA guarantees every wave's LDS reads complete
// before it reaches the end-of-phase barrier -> the post-MFMA barrier was redundant.
// With one barrier, wave A's MFMA overlaps wave B's ds_reads/stage on the same SIMD.
// Phase qq (q&3) computes K-slice kk=qq>>1, M-frags mi=(qq&1)*4+s (s=0..3):
// 4 A ds_reads/phase + 4 B ds_reads on even phases (uniform LDS load, max burst 8).
// Region read-lifetimes: A-buf: q0..q3 (resp q4..q7); B-buf: q0..q2 (resp q4..q6).
// Stage schedule (stage only at a phase STRICTLY after region's last LDS read):
//   q0: A0(t1)   q1: A1(t1)      [A-buf1 last read prev q7]
//   q2: --
//   q3: B0(t0+2) + vmcnt(2)      [B-buf0 last read q2; wait: A(t1),B(t1) landed for q4]
//   q4: B1(t0+2)  q5: A0(t0+2)  q6: A1(t0+2)   [A-buf0 last read q3]
//   q7: B0(t1+2)+B1(t1+2) + vmcnt(4)  [B-buf1 last read q6; wait: A,B(t0+2) for next q0]
// Outstanding-load audit (steady state): enter q0 with B(t1):4; q3-end = 10 -> vmcnt(2)
// keeps B0(t0+2):2; q7-end = 12 -> vmcnt(4) keeps B(t1+2):4.  Tail (pf=false): vmcnt(0)
// at q3 drains A(t1)+B(t1); no stages after. Prologue stages A(0),B(0),B(1): vmcnt(4).
// Raw s_barrier (never __syncthreads) so no compiler vmcnt(0) drain in the loop.
//
// T2 LDS slot-XOR swizzle (rule #21: linear DMA dest + pre-swizzled SOURCE + swz READ):
// physical 16B-slot = logical slot ^ (row&7); staging thread tid loads global slot
// (tid&7)^((tid>>3)&7); frag reads XOR byte col with (lr&7)*16. All row offsets are
// ==0 mod 8 so the involution is consistent end-to-end.
template <typename OutT>
__global__ __launch_bounds__(512, 1) void gemm_nt_8p(const bf16_t* __restrict__ A, int lda, long long sA,
                                                     const bf16_t* __restrict__ Bm, int ldb, long long sB,
                                                     OutT* __restrict__ C, int ldc, long long sC,
                                                     int K, float scale, int swz) {
  __shared__ __align__(16) char lds_raw[131072];

  const int tid = threadIdx.x;
  const int lane = tid & 63, wave = tid >> 6; // 8 waves
  const int wr = wave >> 2, wc = wave & 3;    // 2x4 wave grid, each 128x64
  const int quad = lane >> 4, lr = lane & 15;

  int bx = blockIdx.x, by = blockIdx.y, bz = blockIdx.z;
  if (swz) {
    int Gx = gridDim.x, Gy = gridDim.y, Gz = gridDim.z;
    int i = bx + Gx * (by + Gy * bz);
    int xcd = i & 7, slot = i >> 3;
    int T = Gx * Gy;
    int bpx = Gz >> 3; // batches per XCD (Gz=16 -> 2)
    bz = xcd * bpx + slot / T;
    int t = slot % T;
    bx = t % Gx;
    by = t / Gx;
  }
  const int tileN = bx * 256, tileM = by * 256;
  A += (long long)bz * sA + (long long)tileM * lda;
  Bm += (long long)bz * sB + (long long)tileN * ldb;
  C += (long long)bz * sC;

  // per-thread staging source (pre-swizzled column): thread tid covers
  // row (tid>>3)+j*64+h*128, PHYSICAL slot tid&7 -> GLOBAL slot (tid&7)^((tid>>3)&7)
  const int scol = (((tid & 7) ^ ((tid >> 3) & 7)) * 8);
  const bf16_t* a_src = A + (long long)(tid >> 3) * lda + scol;
  const bf16_t* b_src = Bm + (long long)(tid >> 3) * ldb + scol;

  // LDS dest: linear, wave-uniform base + lane*16 (required by global_load_lds)
  auto STAGE_A = [&](int t, int h) {
    char* base = lds_raw + (t & 1) * 65536 + h * 16384 + wave * 1024;
    const bf16_t* g = a_src + (long long)(h * 128) * lda + t * 64;
    ASYNC_COPY16(g, base);
    ASYNC_COPY16(g + (long long)64 * lda, base + 8192);
  };
  auto STAGE_B = [&](int t, int h) {
    char* base = lds_raw + (t & 1) * 65536 + 32768 + h * 16384 + wave * 1024;
    const bf16_t* g = b_src + (long long)(h * 128) * ldb + t * 64;
    ASYNC_COPY16(g, base);
    ASYNC_COPY16(g + (long long)64 * ldb, base + 8192);
  };

  f32x4 acc[8][4];
#pragma unroll
  for (int i = 0; i < 8; i++)
#pragma unroll
    for (int j = 0; j < 4; j++) acc[i][j] = (f32x4){0.f, 0.f, 0.f, 0.f};

  const int nk = K >> 6;     // K-tiles (even: K=768 -> 12, K=1024 -> 16)
  const int niter = nk >> 1;

  // prologue: stage tile0 fully + B(1); A(1) is staged in-loop at q0/q1.
  // 12 loads issued; vmcnt(4) -> first 8 (A(0),B(0)) landed; B(1):4 outstanding.
  STAGE_A(0, 0); STAGE_A(0, 1); STAGE_B(0, 0); STAGE_B(0, 1);
  STAGE_B(1, 0); STAGE_B(1, 1);
  asm volatile("s_waitcnt vmcnt(4)" ::: "memory");
  __builtin_amdgcn_s_barrier();

  for (int it = 0; it < niter; ++it) {
    const int t1 = 2 * it + 1;
    const bool pf = (t1 + 1) < nk; // next K-tile pair exists
    bf16x8 bfr[4];                 // current-kk B frags (reloaded at qq==0,2; held 2 phases)
#pragma unroll
    for (int q = 0; q < 8; ++q) {
      const int hb = q >> 2, qq = q & 3;
      const int kk = qq >> 1, mh = qq & 1;
      const bf16_t* As = (const bf16_t*)(lds_raw + hb * 65536 + wr * 16384);
      const bf16_t* Bs = (const bf16_t*)(lds_raw + hb * 65536 + 32768 + (wc >> 1) * 16384);
      // stage first (max DMA head start); schedule per header comment
      if (q == 0) {
        STAGE_A(t1, 0);
      } else if (q == 1) {
        STAGE_A(t1, 1);
      } else if (q == 3) {
        if (pf) STAGE_B(t1 + 1, 0);
      } else if (q == 4) {
        if (pf) STAGE_B(t1 + 1, 1);
      } else if (q == 5) {
        if (pf) STAGE_A(t1 + 1, 0);
      } else if (q == 6) {
        if (pf) STAGE_A(t1 + 1, 1);
      } else if (q == 7) {
        if (pf) { STAGE_B(t1 + 2, 0); STAGE_B(t1 + 2, 1); }
      }
      // B frags for this K-slice (even phases only)
      if (mh == 0) {
#pragma unroll
        for (int nj = 0; nj < 4; ++nj)
          bfr[nj] = *(const bf16x8*)&Bs[((wc & 1) * 64 + nj * 16 + lr) * 64 +
                                        ((kk * 32 + quad * 8) ^ ((lr & 7) * 8))];
      }
      bf16x8 af[4];
#pragma unroll
      for (int s = 0; s < 4; ++s)
        af[s] = *(const bf16x8*)&As[((mh * 4 + s) * 16 + lr) * 64 +
                                    ((kk * 32 + quad * 8) ^ ((lr & 7) * 8))];
      __builtin_amdgcn_s_setprio(1);
#pragma unroll
      for (int s = 0; s < 4; ++s)
#pragma unroll
        for (int nj = 0; nj < 4; ++nj)
          acc[mh * 4 + s][nj] =
              __builtin_amdgcn_mfma_f32_16x16x32_bf16(af[s], bfr[nj], acc[mh * 4 + s][nj], 0, 0, 0);
      __builtin_amdgcn_s_setprio(0);
      if (q == 3) {
        if (pf) asm volatile("s_waitcnt vmcnt(2)" ::: "memory"); // A(t1),B(t1) landed
        else    asm volatile("s_waitcnt vmcnt(0)" ::: "memory"); // tail: full drain
      } else if (q == 7) {
        if (pf) asm volatile("s_waitcnt vmcnt(4)" ::: "memory"); // A,B(t0+2) landed
      }
      __builtin_amdgcn_s_barrier();
    }
  }
  __syncthreads(); // full drain before LDS repurpose (epilogue)

  // ---- epilogue: per-wave repack, 16-row chunks (per-wave private 16x68 f32) ----
  float* epi = (float*)lds_raw + wave * (16 * 68);
#pragma unroll
  for (int mi = 0; mi < 8; ++mi) {
#pragma unroll
    for (int nj = 0; nj < 4; ++nj)
#pragma unroll
      for (int r = 0; r < 4; ++r)
        epi[(quad * 4 + r) * 68 + nj * 16 + lr] = acc[mi][nj][r] * scale;
    if constexpr (sizeof(OutT) == 4) {
#pragma unroll
      for (int seg = 0; seg < 4; seg++) {
        int lrow = seg * 4 + (lane >> 4);
        f32x4 v = *(const f32x4*)&epi[lrow * 68 + (lane & 15) * 4];
        long long grow = tileM + wr * 128 + mi * 16 + lrow;
        int gcol = tileN + wc * 64 + (lane & 15) * 4;
        *(f32x4*)&C[grow * ldc + gcol] = v;
      }
    } else {
#pragma unroll
      for (int seg = 0; seg < 2; seg++) {
        int lrow = seg * 8 + (lane >> 3);
        const float* p = &epi[lrow * 68 + (lane & 7) * 8];
        f32x4 v0 = *(const f32x4*)&p[0];
        f32x4 v1 = *(const f32x4*)&p[4];
        bf16x8 o;
#pragma unroll
        for (int j = 0; j < 4; j++) { o[j] = (bf16_t)v0[j]; o[j + 4] = (bf16_t)v1[j]; }
        long long grow = tileM + wr * 128 + mi * 16 + lrow;
        int gcol = tileN + wc * 64 + (lane & 7) * 8;
        *(bf16x8*)&C[grow * ldc + gcol] = o;
      }
    }
  }
}

extern "C" void kernel_launch(void* const* d_in, const int* in_sizes, int n_in,
                              void* d_out, int out_size, void* d_ws, size_t ws_size,
                              hipStream_t stream) {
  const float* x = (const float*)d_in[0];      // [B][N][D]
  const float* y = (const float*)d_in[1];      // [B][N][D]
  const float* coords = (const float*)d_in[2]; // [N][N][6]
  const float* W = (const float*)d_in[3];      // [D][D]
  const float* pemb = (const float*)d_in[4];   // [N][6]
  const float* gating = (const float*)d_in[5];
  const float* temp = (const float*)d_in[6];
  float* out = (float*)d_out;
  float* hmap = out + (size_t)B * N * D;

  char* ws = (char*)d_ws;
  bf16_t* xb = (bf16_t*)(ws + 0);          // 24 MB
  bf16_t* yb = (bf16_t*)(ws + 25165824);   // 24 MB
  bf16_t* yT = (bf16_t*)(ws + 50331648);   // 24 MB
  bf16_t* Wb = (bf16_t*)(ws + 75497472);   // 1.125 MB
  bf16_t* kb = (bf16_t*)(ws + 76677120);   // 24 MB
  float* pos = (float*)(ws + 101842944);   // 4 MB
  float* S   = (float*)(ws + 106037248);   // 64 MB  (attn bf16 written in place)

  const int BND = B * N * D; // 12582912

  cast_f32_bf16_4<<<BND / 4 / 256, 256, 0, stream>>>((const float4*)x, (bf16x4*)xb, BND / 4);
  cast_f32_bf16_4<<<(D * D / 4 + 255) / 256, 256, 0, stream>>>((const float4*)W, (bf16x4*)Wb, D * D / 4);
  cast_transpose_y<<<dim3(D / 32, N / 32, B), 256, 0, stream>>>(y, yb, yT);
  pos_softmax_k<<<N, 256, 0, stream>>>(coords, pemb, pos);

  // K1: kb[16384][768] = yb * Wb^T   (M=16384, N=768, K=768)
  gemm_nt_8p<bf16_t><<<dim3(D / 256, (B * N) / 256, 1), 512, 0, stream>>>(
      yb, D, 0LL, Wb, D, 0LL, kb, D, 0LL, D, 1.0f, 0);

  // K3: S[b][n][m] = SCALE * x[b] * k[b]^T   (M=1024, N=1024, K=768) -> 256 blocks = 1/CU
  gemm_nt_8p<float><<<dim3(N / 256, N / 256, B), 512, 0, stream>>>(
      xb, D, (long long)N * D, kb, D, (long long)N * D, S, N, (long long)N * N, D, SCALE, 1);

  // K4: softmax + gate + entropy; attn bf16 in place (row stride 2048 bf16)
  attn_entropy_k<<<B * N, 256, 0, stream>>>(S, pos, gating, temp, hmap);

  // K5: out[b][n][d] = attn[b] * y[b]   (M=1024, N=768, K=1024; B-operand = yT)
  gemm_nt_8p<float><<<dim3(D / 256, N / 256, B), 512, 0, stream>>>(
      (const bf16_t*)S, 2 * N, (long long)N * 2 * N, yT, N, (long long)N * D, out, D, (long long)N * D, N, 1.0f, 1);
}

// Round 5
// 289.699 us; speedup vs baseline: 1.0382x; 1.0382x over previous
//
#include <hip/hip_runtime.h>
#include <hip/hip_bf16.h>
#include <cstdint>

typedef __bf16 bf16_t;
typedef __bf16 bf16x8 __attribute__((ext_vector_type(8)));
typedef __bf16 bf16x4 __attribute__((ext_vector_type(4)));
typedef float f32x4 __attribute__((ext_vector_type(4)));

static constexpr int B = 16, N = 1024, D = 768;
static constexpr float SCALE = 0.03608439182435161f; // 768^-0.5

// async global->LDS, 16B per lane, wave-uniform LDS base + lane*16
#define ASYNC_COPY16(gptr, lptr)                                                          \
  __builtin_amdgcn_global_load_lds((const __attribute__((address_space(1))) void*)(gptr), \
                                   (__attribute__((address_space(3))) void*)(lptr), 16, 0, 0)

// ---------------- helpers ----------------
__device__ __forceinline__ float wave_red_max(float v) {
#pragma unroll
  for (int o = 32; o > 0; o >>= 1) v = fmaxf(v, __shfl_down(v, o, 64));
  return v;
}
__device__ __forceinline__ float wave_red_sum(float v) {
#pragma unroll
  for (int o = 32; o > 0; o >>= 1) v += __shfl_down(v, o, 64);
  return v;
}
__device__ __forceinline__ float block_max(float v, float* sm) {
  v = wave_red_max(v);
  int lane = threadIdx.x & 63, w = threadIdx.x >> 6;
  if (lane == 0) sm[w] = v;
  __syncthreads();
  return fmaxf(fmaxf(sm[0], sm[1]), fmaxf(sm[2], sm[3]));
}
__device__ __forceinline__ float block_sum(float v, float* sm) {
  v = wave_red_sum(v);
  int lane = threadIdx.x & 63, w = threadIdx.x >> 6;
  if (lane == 0) sm[w] = v;
  __syncthreads();
  return sm[0] + sm[1] + sm[2] + sm[3];
}

// ---------------- cast fp32 -> bf16 (4 elems / thread) ----------------
__global__ __launch_bounds__(256) void cast_f32_bf16_4(const float4* __restrict__ in,
                                                       bf16x4* __restrict__ out, int n4) {
  int i = blockIdx.x * 256 + threadIdx.x;
  if (i < n4) {
    float4 v = in[i];
    bf16x4 o;
    o.x = (bf16_t)v.x; o.y = (bf16_t)v.y; o.z = (bf16_t)v.z; o.w = (bf16_t)v.w;
    out[i] = o;
  }
}

// ---------------- fused cast+transpose: y f32 [B][N][D] -> yb bf16 [B][N][D] + yT bf16 [B][D][N]
__global__ __launch_bounds__(256) void cast_transpose_y(const float* __restrict__ y,
                                                        bf16_t* __restrict__ yb,
                                                        bf16_t* __restrict__ yT) {
  __shared__ bf16_t t[32][33];
  int b = blockIdx.z;
  int d0 = blockIdx.x * 32;
  int n0 = blockIdx.y * 32;
  int tx = threadIdx.x & 31;
  int ty = threadIdx.x >> 5; // 0..7
  const float* src = y + (size_t)b * N * D;
  bf16_t* dstN = yb + (size_t)b * N * D;
  bf16_t* dstT = yT + (size_t)b * N * D;
#pragma unroll
  for (int r = 0; r < 4; r++) {
    int n = n0 + ty + r * 8;
    float v = src[(size_t)n * D + d0 + tx];
    bf16_t h = (bf16_t)v;
    t[ty + r * 8][tx] = h;
    dstN[(size_t)n * D + d0 + tx] = h;
  }
  __syncthreads();
#pragma unroll
  for (int r = 0; r < 4; r++) {
    int d = d0 + ty + r * 8;
    dstT[(size_t)d * N + n0 + tx] = t[tx][ty + r * 8];
  }
}

// ---------------- positional softmax: pos[p][n] ----------------
__global__ __launch_bounds__(256) void pos_softmax_k(const float* __restrict__ coords,
                                                     const float* __restrict__ pemb,
                                                     float* __restrict__ pos) {
  __shared__ float sm1[4], sm2[4];
  int p = blockIdx.x;
  int tid = threadIdx.x;
  float e[6];
#pragma unroll
  for (int k = 0; k < 6; k++) e[k] = pemb[p * 6 + k];
  float v[4];
#pragma unroll
  for (int i = 0; i < 4; i++) {
    int n = tid + i * 256;
    const float* c = coords + ((size_t)p * N + n) * 6;
    float s = 0.f;
#pragma unroll
    for (int k = 0; k < 6; k++) s += c[k] * e[k];
    v[i] = s;
  }
  float m = block_max(fmaxf(fmaxf(v[0], v[1]), fmaxf(v[2], v[3])), sm1);
  float ex[4], ls = 0.f;
#pragma unroll
  for (int i = 0; i < 4; i++) { ex[i] = __expf(v[i] - m); ls += ex[i]; }
  float sum = block_sum(ls, sm2);
  float inv = 1.f / sum;
#pragma unroll
  for (int i = 0; i < 4; i++) pos[(size_t)p * N + tid + i * 256] = ex[i] * inv;
}

// ---------------- softmax + gate + entropy; writes attn bf16 in place ----------------
__global__ __launch_bounds__(256) void attn_entropy_k(float* __restrict__ S,
                                                      const float* __restrict__ pos,
                                                      const float* __restrict__ gating,
                                                      const float* __restrict__ temp,
                                                      float* __restrict__ hmap) {
  __shared__ float sm1[4], sm2[4], sm3[4];
  size_t row = blockIdx.x; // 0 .. B*N-1
  int q = (int)(row & (size_t)(N - 1));
  int tid = threadIdx.x;
  float* Srow = S + row * N;
  float g = 1.f / (1.f + __expf(-gating[0]));
  float s[4];
#pragma unroll
  for (int i = 0; i < 4; i++) s[i] = Srow[tid + i * 256];
  float m = block_max(fmaxf(fmaxf(s[0], s[1]), fmaxf(s[2], s[3])), sm1);
  float e[4], ls = 0.f;
#pragma unroll
  for (int i = 0; i < 4; i++) { e[i] = __expf(s[i] - m); ls += e[i]; }
  float sum = block_sum(ls, sm2);
  float inv = 1.f / sum;
  const float* prow = pos + (size_t)q * N;
  float a[4], ent = 0.f;
#pragma unroll
  for (int i = 0; i < 4; i++) {
    float patch = e[i] * inv;
    float ps = prow[tid + i * 256];
    a[i] = (1.f - g) * patch + g * ps;
    ent += -a[i] * __logf(a[i] + 1e-8f);
  }
  float E = block_sum(ent, sm3);
  __syncthreads(); // all reads of Srow complete before bf16 overwrite
  bf16_t* arow = (bf16_t*)Srow; // in-place: bf16 row lives in first 2 KB of the 4 KB fp32 slot
#pragma unroll
  for (int i = 0; i < 4; i++) arow[tid + i * 256] = (bf16_t)a[i];
  // hmap = 2*(1 - sigmoid(z)) = 2/(1+exp(z)),  z = temp*E
  if (tid == 0) hmap[row] = 2.f / (1.f + __expf(temp[0] * E));
}

// ---------------- NT GEMM: 256 x (NJ*64) tile, BK=64, 8 waves, 8-phase counted-vmcnt
// C[M][Nc] = A[M][K] * B[Nc][K]^T * scale.   REQUIRES: K % 128 == 0 (nk even).
// NJ = N-frags per wave: NJ=4 -> BN=256 (R3-identical), NJ=3 -> BN=192 (fills 256-CU
// grids for N=768 outputs: 768/192=4 col-tiles).
// 8 waves in 2(M)x4(N); each wave owns 128 x NJ*16 (acc[8][NJ] of 16x16 frags).
// LDS ring: 2 K-tile buffers x (A 256x64 + B BN x 64) bf16.
// Staging granularity: 8 KB groups (64 rows x 64 cols bf16 = 512 thr x 16 B).
// A = 4 groups/K-tile, B = NJ groups/K-tile.
// Iteration i computes K-tiles t0=2i (buf0, q0-3) and t1=2i+1 (buf1, q4-7).
// Stage schedule (stage only after the staged region's last read has passed a barrier):
//   q0: A(t1) g0,g1   q1: A(t1) g2,g3     [A-buf1 last read: prev iter q7]
//   q2: B(t0+2) g0,g1 q3: B(t0+2) rest + vmcnt(NJ)  [B-buf0 last read q0; A(t1),B(t1) landed]
//   q4: A(t0+2) g0,g1 q5: A(t0+2) g2,g3   [A-buf0 last read q3]
//   q6: B(t1+2) g0,g1 q7: B(t1+2) rest + vmcnt(NJ)  [B-buf1 last read q4; A,B(t0+2) landed]
// Steady-state audit: enter q0 with B(t1):NJ outstanding; q3-end = NJ+4+NJ -> vmcnt(NJ)
// keeps B(t0+2):NJ; q7-end likewise. Tail (pf=false): vmcnt(0) at q3; no stages after.
// Prologue stages A(0),B(0),B(1): vmcnt(NJ). Raw s_barrier only (no compiler vmcnt(0)).
// Per-phase: {B-frags(q0/q4), A-frags, stage, [vmcnt], bar, setprio, 2*NJ*2 MFMA, setprio, bar}.
//
// T2 LDS slot-XOR swizzle (rule #21: linear DMA dest + pre-swizzled SOURCE + swz READ):
// physical 16B-slot = logical slot ^ (row&7); staging thread tid loads global slot
// (tid&7)^((tid>>3)&7); frag reads XOR byte col with (lr&7)*16. All row offsets are
// ==0 mod 8 so the involution is consistent end-to-end.
template <typename OutT, int NJ>
__global__ __launch_bounds__(512, 1) void gemm_nt_8p(const bf16_t* __restrict__ A, int lda, long long sA,
                                                     const bf16_t* __restrict__ Bm, int ldb, long long sB,
                                                     OutT* __restrict__ C, int ldc, long long sC,
                                                     int K, float scale, int swz) {
  constexpr int BN = NJ * 64;
  constexpr int BUFSZ = 32768 + NJ * 8192; // A-region + B-region bytes per K-tile buffer
  __shared__ __align__(16) char lds_raw[2 * BUFSZ];

  const int tid = threadIdx.x;
  const int lane = tid & 63, wave = tid >> 6; // 8 waves
  const int wr = wave >> 2, wc = wave & 3;    // 2x4 wave grid, each 128 x NJ*16
  const int quad = lane >> 4, lr = lane & 15;

  int bx = blockIdx.x, by = blockIdx.y, bz = blockIdx.z;
  if (swz) {
    int Gx = gridDim.x, Gy = gridDim.y, Gz = gridDim.z;
    int i = bx + Gx * (by + Gy * bz);
    int xcd = i & 7, slot = i >> 3;
    int T = Gx * Gy;
    int bpx = Gz >> 3; // batches per XCD (Gz=16 -> 2)
    bz = xcd * bpx + slot / T;
    int t = slot % T;
    bx = t % Gx;
    by = t / Gx;
  }
  const int tileN = bx * BN, tileM = by * 256;
  A += (long long)bz * sA + (long long)tileM * lda;
  Bm += (long long)bz * sB + (long long)tileN * ldb;
  C += (long long)bz * sC;

  // per-thread staging source (pre-swizzled column): thread tid covers
  // row (tid>>3)+g*64, PHYSICAL slot tid&7 -> GLOBAL slot (tid&7)^((tid>>3)&7)
  const int scol = (((tid & 7) ^ ((tid >> 3) & 7)) * 8);
  const bf16_t* a_src = A + (long long)(tid >> 3) * lda + scol;
  const bf16_t* b_src = Bm + (long long)(tid >> 3) * ldb + scol;

  // LDS dest: linear, wave-uniform base + lane*16 (required by global_load_lds)
  auto STAGE_A = [&](int t, int h) { // h = half (2 groups of 64 rows)
    char* base = lds_raw + (t & 1) * BUFSZ + h * 16384 + wave * 1024;
    const bf16_t* g = a_src + (long long)(h * 128) * lda + t * 64;
    ASYNC_COPY16(g, base);
    ASYNC_COPY16(g + (long long)64 * lda, base + 8192);
  };
  auto STAGE_B_G = [&](int t, int g) { // one 64-row group
    char* base = lds_raw + (t & 1) * BUFSZ + 32768 + g * 8192 + wave * 1024;
    const bf16_t* gp = b_src + (long long)(g * 64) * ldb + t * 64;
    ASYNC_COPY16(gp, base);
  };
  auto WAIT_NJ = [&]() {
    if constexpr (NJ == 4) asm volatile("s_waitcnt vmcnt(4)" ::: "memory");
    else                   asm volatile("s_waitcnt vmcnt(3)" ::: "memory");
  };

  f32x4 acc[8][NJ];
#pragma unroll
  for (int i = 0; i < 8; i++)
#pragma unroll
    for (int j = 0; j < NJ; j++) acc[i][j] = (f32x4){0.f, 0.f, 0.f, 0.f};

  const int nk = K >> 6;     // K-tiles (even: K=768 -> 12, K=1024 -> 16)
  const int niter = nk >> 1;

  // prologue: stage tile0 fully + B(1); A(1) is staged in-loop at q0/q1.
  STAGE_A(0, 0); STAGE_A(0, 1);
#pragma unroll
  for (int g = 0; g < NJ; g++) STAGE_B_G(0, g);
#pragma unroll
  for (int g = 0; g < NJ; g++) STAGE_B_G(1, g);
  WAIT_NJ();
  __builtin_amdgcn_s_barrier();

  for (int it = 0; it < niter; ++it) {
    const int t1 = 2 * it + 1;
    const bool pf = (t1 + 1) < nk; // next K-tile pair exists
    bf16x8 bfr[NJ][2];             // B frags: loaded at q0/q4, held 4 phases
#pragma unroll
    for (int q = 0; q < 8; ++q) {
      const int hb = q >> 2, qq = q & 3;
      const bf16_t* As = (const bf16_t*)(lds_raw + hb * BUFSZ + wr * 16384);
      const bf16_t* Bs = (const bf16_t*)(lds_raw + hb * BUFSZ + 32768);
      if (qq == 0) {
#pragma unroll
        for (int nj = 0; nj < NJ; ++nj)
#pragma unroll
          for (int kk = 0; kk < 2; ++kk)
            bfr[nj][kk] = *(const bf16x8*)&Bs[(wc * (NJ * 16) + nj * 16 + lr) * 64 +
                                              ((kk * 32 + quad * 8) ^ ((lr & 7) * 8))];
      }
      bf16x8 af[2][2];
#pragma unroll
      for (int s = 0; s < 2; ++s)
#pragma unroll
        for (int kk = 0; kk < 2; ++kk)
          af[s][kk] = *(const bf16x8*)&As[((qq * 2 + s) * 16 + lr) * 64 +
                                          ((kk * 32 + quad * 8) ^ ((lr & 7) * 8))];
      // stage: see schedule in header comment
      if (q == 0) {
        STAGE_A(t1, 0);
      } else if (q == 1) {
        STAGE_A(t1, 1);
      } else if (q == 2) {
        if (pf) { STAGE_B_G(t1 + 1, 0); STAGE_B_G(t1 + 1, 1); }
      } else if (q == 3) {
        if (pf) {
          STAGE_B_G(t1 + 1, 2);
          if constexpr (NJ == 4) STAGE_B_G(t1 + 1, 3);
          WAIT_NJ();   // A(t1),B(t1) landed
        } else {
          asm volatile("s_waitcnt vmcnt(0)" ::: "memory"); // tail: drain (A(t1) landed)
        }
      } else if (q == 4) {
        if (pf) STAGE_A(t1 + 1, 0);
      } else if (q == 5) {
        if (pf) STAGE_A(t1 + 1, 1);
      } else if (q == 6) {
        if (pf) { STAGE_B_G(t1 + 2, 0); STAGE_B_G(t1 + 2, 1); }
      } else { // q == 7
        if (pf) {
          STAGE_B_G(t1 + 2, 2);
          if constexpr (NJ == 4) STAGE_B_G(t1 + 2, 3);
          WAIT_NJ();   // A(t0+2),B(t0+2) landed
        }
      }
      __builtin_amdgcn_s_barrier();
      __builtin_amdgcn_s_setprio(1);
#pragma unroll
      for (int s = 0; s < 2; ++s)
#pragma unroll
        for (int nj = 0; nj < NJ; ++nj)
#pragma unroll
          for (int kk = 0; kk < 2; ++kk)
            acc[qq * 2 + s][nj] =
                __builtin_amdgcn_mfma_f32_16x16x32_bf16(af[s][kk], bfr[nj][kk], acc[qq * 2 + s][nj], 0, 0, 0);
      __builtin_amdgcn_s_setprio(0);
      __builtin_amdgcn_s_barrier();
    }
  }
  __syncthreads(); // full drain before LDS repurpose (epilogue)

  // ---- epilogue: per-wave repack, 16-row chunks (per-wave private 16x68 f32) ----
  float* epi = (float*)lds_raw + wave * (16 * 68);
#pragma unroll
  for (int mi = 0; mi < 8; ++mi) {
#pragma unroll
    for (int nj = 0; nj < NJ; ++nj)
#pragma unroll
      for (int r = 0; r < 4; ++r)
        epi[(quad * 4 + r) * 68 + nj * 16 + lr] = acc[mi][nj][r] * scale;
    if constexpr (NJ == 4) {
      if constexpr (sizeof(OutT) == 4) {
#pragma unroll
        for (int seg = 0; seg < 4; seg++) {
          int lrow = seg * 4 + (lane >> 4);
          f32x4 v = *(const f32x4*)&epi[lrow * 68 + (lane & 15) * 4];
          long long grow = tileM + wr * 128 + mi * 16 + lrow;
          int gcol = tileN + wc * 64 + (lane & 15) * 4;
          *(f32x4*)&C[grow * ldc + gcol] = v;
        }
      } else {
#pragma unroll
        for (int seg = 0; seg < 2; seg++) {
          int lrow = seg * 8 + (lane >> 3);
          const float* p = &epi[lrow * 68 + (lane & 7) * 8];
          f32x4 v0 = *(const f32x4*)&p[0];
          f32x4 v1 = *(const f32x4*)&p[4];
          bf16x8 o;
#pragma unroll
          for (int j = 0; j < 4; j++) { o[j] = (bf16_t)v0[j]; o[j + 4] = (bf16_t)v1[j]; }
          long long grow = tileM + wr * 128 + mi * 16 + lrow;
          int gcol = tileN + wc * 64 + (lane & 7) * 8;
          *(bf16x8*)&C[grow * ldc + gcol] = o;
        }
      }
    } else { // NJ == 3: wave owns 48 cols; 48 active lanes per pass
      if constexpr (sizeof(OutT) == 4) {
#pragma unroll
        for (int seg = 0; seg < 4; seg++) {
          if (lane < 48) {
            int lrow = seg * 4 + lane / 12;
            int c4 = (lane % 12) * 4;
            f32x4 v = *(const f32x4*)&epi[lrow * 68 + c4];
            long long grow = tileM + wr * 128 + mi * 16 + lrow;
            int gcol = tileN + wc * 48 + c4;
            *(f32x4*)&C[grow * ldc + gcol] = v;
          }
        }
      } else {
#pragma unroll
        for (int seg = 0; seg < 2; seg++) {
          if (lane < 48) {
            int lrow = seg * 8 + lane / 6;
            int c8 = (lane % 6) * 8;
            const float* p = &epi[lrow * 68 + c8];
            f32x4 v0 = *(const f32x4*)&p[0];
            f32x4 v1 = *(const f32x4*)&p[4];
            bf16x8 o;
#pragma unroll
            for (int j = 0; j < 4; j++) { o[j] = (bf16_t)v0[j]; o[j + 4] = (bf16_t)v1[j]; }
            long long grow = tileM + wr * 128 + mi * 16 + lrow;
            int gcol = tileN + wc * 48 + c8;
            *(bf16x8*)&C[grow * ldc + gcol] = o;
          }
        }
      }
    }
  }
}

extern "C" void kernel_launch(void* const* d_in, const int* in_sizes, int n_in,
                              void* d_out, int out_size, void* d_ws, size_t ws_size,
                              hipStream_t stream) {
  const float* x = (const float*)d_in[0];      // [B][N][D]
  const float* y = (const float*)d_in[1];      // [B][N][D]
  const float* coords = (const float*)d_in[2]; // [N][N][6]
  const float* W = (const float*)d_in[3];      // [D][D]
  const float* pemb = (const float*)d_in[4];   // [N][6]
  const float* gating = (const float*)d_in[5];
  const float* temp = (const float*)d_in[6];
  float* out = (float*)d_out;
  float* hmap = out + (size_t)B * N * D;

  char* ws = (char*)d_ws;
  bf16_t* xb = (bf16_t*)(ws + 0);          // 24 MB
  bf16_t* yb = (bf16_t*)(ws + 25165824);   // 24 MB
  bf16_t* yT = (bf16_t*)(ws + 50331648);   // 24 MB
  bf16_t* Wb = (bf16_t*)(ws + 75497472);   // 1.125 MB
  bf16_t* kb = (bf16_t*)(ws + 76677120);   // 24 MB
  float* pos = (float*)(ws + 101842944);   // 4 MB
  float* S   = (float*)(ws + 106037248);   // 64 MB  (attn bf16 written in place)

  const int BND = B * N * D; // 12582912

  cast_f32_bf16_4<<<BND / 4 / 256, 256, 0, stream>>>((const float4*)x, (bf16x4*)xb, BND / 4);
  cast_f32_bf16_4<<<(D * D / 4 + 255) / 256, 256, 0, stream>>>((const float4*)W, (bf16x4*)Wb, D * D / 4);
  cast_transpose_y<<<dim3(D / 32, N / 32, B), 256, 0, stream>>>(y, yb, yT);
  pos_softmax_k<<<N, 256, 0, stream>>>(coords, pemb, pos);

  // K1: kb[16384][768] = yb * Wb^T   (M=16384, N=768, K=768) -> BN=192, 4x64 = 256 blocks
  gemm_nt_8p<bf16_t, 3><<<dim3(D / 192, (B * N) / 256, 1), 512, 0, stream>>>(
      yb, D, 0LL, Wb, D, 0LL, kb, D, 0LL, D, 1.0f, 0);

  // K3: S[b][n][m] = SCALE * x[b] * k[b]^T   (M=1024, N=1024, K=768) -> 256 blocks = 1/CU
  gemm_nt_8p<float, 4><<<dim3(N / 256, N / 256, B), 512, 0, stream>>>(
      xb, D, (long long)N * D, kb, D, (long long)N * D, S, N, (long long)N * N, D, SCALE, 1);

  // K4: softmax + gate + entropy; attn bf16 in place (row stride 2048 bf16)
  attn_entropy_k<<<B * N, 256, 0, stream>>>(S, pos, gating, temp, hmap);

  // K5: out[b][n][d] = attn[b] * y[b]   (M=1024, N=768, K=1024) -> BN=192, 4x4x16 = 256 blocks
  gemm_nt_8p<float, 3><<<dim3(D / 192, N / 256, B), 512, 0, stream>>>(
      (const bf16_t*)S, 2 * N, (long long)N * 2 * N, yT, N, (long long)N * D, out, D, (long long)N * D, N, 1.0f, 1);
}

// Round 6
// 286.165 us; speedup vs baseline: 1.0510x; 1.0124x over previous
//
#include <hip/hip_runtime.h>
#include <hip/hip_bf16.h>
#include <cstdint>

typedef __bf16 bf16_t;
typedef __bf16 bf16x8 __attribute__((ext_vector_type(8)));
typedef __bf16 bf16x4 __attribute__((ext_vector_type(4)));
typedef float f32x4 __attribute__((ext_vector_type(4)));
typedef _Float16 f16x4 __attribute__((ext_vector_type(4)));

static constexpr int B = 16, N = 1024, D = 768;
static constexpr float SCALE = 0.03608439182435161f; // 768^-0.5

// async global->LDS, 16B per lane, wave-uniform LDS base + lane*16
#define ASYNC_COPY16(gptr, lptr)                                                          \
  __builtin_amdgcn_global_load_lds((const __attribute__((address_space(1))) void*)(gptr), \
                                   (__attribute__((address_space(3))) void*)(lptr), 16, 0, 0)

// ---------------- helpers ----------------
__device__ __forceinline__ float wave_red_max(float v) {
#pragma unroll
  for (int o = 32; o > 0; o >>= 1) v = fmaxf(v, __shfl_down(v, o, 64));
  return v;
}
__device__ __forceinline__ float wave_red_sum(float v) {
#pragma unroll
  for (int o = 32; o > 0; o >>= 1) v += __shfl_down(v, o, 64);
  return v;
}
__device__ __forceinline__ float block_max(float v, float* sm) {
  v = wave_red_max(v);
  int lane = threadIdx.x & 63, w = threadIdx.x >> 6;
  if (lane == 0) sm[w] = v;
  __syncthreads();
  return fmaxf(fmaxf(sm[0], sm[1]), fmaxf(sm[2], sm[3]));
}
__device__ __forceinline__ float block_sum(float v, float* sm) {
  v = wave_red_sum(v);
  int lane = threadIdx.x & 63, w = threadIdx.x >> 6;
  if (lane == 0) sm[w] = v;
  __syncthreads();
  return sm[0] + sm[1] + sm[2] + sm[3];
}

// ---------------- cast fp32 -> bf16 (4 elems / thread) ----------------
__global__ __launch_bounds__(256) void cast_f32_bf16_4(const float4* __restrict__ in,
                                                       bf16x4* __restrict__ out, int n4) {
  int i = blockIdx.x * 256 + threadIdx.x;
  if (i < n4) {
    float4 v = in[i];
    bf16x4 o;
    o.x = (bf16_t)v.x; o.y = (bf16_t)v.y; o.z = (bf16_t)v.z; o.w = (bf16_t)v.w;
    out[i] = o;
  }
}

// ---------------- fused cast+transpose: y f32 [B][N][D] -> yb bf16 [B][N][D] + yT bf16 [B][D][N]
// 64x64 tiles, float4 reads (16 B/lane), bf16x4 writes (8 B/lane) on both outputs.
// LDS [64][68] bf16: row stride 136 B (8B-aligned rows); gather-phase bank pattern
// (4i+j)*34+col/2 -> lanes hit 4i%32 pairs = free 2-way.
__global__ __launch_bounds__(256) void cast_transpose_y(const float* __restrict__ y,
                                                        bf16_t* __restrict__ yb,
                                                        bf16_t* __restrict__ yT) {
  __shared__ bf16_t t[64][68];
  int b = blockIdx.z;
  int d0 = blockIdx.x * 64;
  int n0 = blockIdx.y * 64;
  int tx = threadIdx.x & 15;  // 16 col-groups of 4 f32
  int ty = threadIdx.x >> 4;  // 16 rows
  const float* src = y + (size_t)b * N * D;
  bf16_t* dstN = yb + (size_t)b * N * D;
  bf16_t* dstT = yT + (size_t)b * N * D;
#pragma unroll
  for (int r = 0; r < 4; r++) {
    int n = n0 + ty + r * 16;
    float4 v = *(const float4*)&src[(size_t)n * D + d0 + tx * 4];
    bf16x4 h;
    h.x = (bf16_t)v.x; h.y = (bf16_t)v.y; h.z = (bf16_t)v.z; h.w = (bf16_t)v.w;
    *(bf16x4*)&dstN[(size_t)n * D + d0 + tx * 4] = h;
    *(bf16x4*)&t[ty + r * 16][tx * 4] = h;
  }
  __syncthreads();
#pragma unroll
  for (int w = 0; w < 4; w++) {
    int dd = (threadIdx.x >> 4) + w * 16; // 0..63 within tile
    int ng = (threadIdx.x & 15) * 4;      // 4 consecutive n
    bf16x4 o;
    o.x = t[ng + 0][dd]; o.y = t[ng + 1][dd]; o.z = t[ng + 2][dd]; o.w = t[ng + 3][dd];
    *(bf16x4*)&dstT[(size_t)(d0 + dd) * N + n0 + ng] = o;
  }
}

// ---------------- positional softmax: pos[p][n] ----------------
__global__ __launch_bounds__(256) void pos_softmax_k(const float* __restrict__ coords,
                                                     const float* __restrict__ pemb,
                                                     float* __restrict__ pos) {
  __shared__ float sm1[4], sm2[4];
  int p = blockIdx.x;
  int tid = threadIdx.x;
  float e[6];
#pragma unroll
  for (int k = 0; k < 6; k++) e[k] = pemb[p * 6 + k];
  float v[4];
#pragma unroll
  for (int i = 0; i < 4; i++) {
    int n = tid + i * 256;
    const float* c = coords + ((size_t)p * N + n) * 6;
    float s = 0.f;
#pragma unroll
    for (int k = 0; k < 6; k++) s += c[k] * e[k];
    v[i] = s;
  }
  float m = block_max(fmaxf(fmaxf(v[0], v[1]), fmaxf(v[2], v[3])), sm1);
  float ex[4], ls = 0.f;
#pragma unroll
  for (int i = 0; i < 4; i++) { ex[i] = __expf(v[i] - m); ls += ex[i]; }
  float sum = block_sum(ls, sm2);
  float inv = 1.f / sum;
#pragma unroll
  for (int i = 0; i < 4; i++) pos[(size_t)p * N + tid + i * 256] = ex[i] * inv;
}

// ---------------- softmax + gate + entropy; S is f16 scores, attn bf16 in place ----
// Thread tid owns elements [4*tid, 4*tid+4): 8B coalesced f16 load, f32 math,
// 8B bf16 store over the same bytes (no cross-thread hazard).
__global__ __launch_bounds__(256) void attn_entropy_k(_Float16* __restrict__ S,
                                                      const float* __restrict__ pos,
                                                      const float* __restrict__ gating,
                                                      const float* __restrict__ temp,
                                                      float* __restrict__ hmap) {
  __shared__ float sm1[4], sm2[4], sm3[4];
  size_t row = blockIdx.x; // 0 .. B*N-1
  int q = (int)(row & (size_t)(N - 1));
  int tid = threadIdx.x;
  _Float16* Srow = S + row * N;
  float g = 1.f / (1.f + __expf(-gating[0]));
  f16x4 v = *(const f16x4*)&Srow[tid * 4];
  float s[4];
#pragma unroll
  for (int i = 0; i < 4; i++) s[i] = (float)v[i];
  float m = block_max(fmaxf(fmaxf(s[0], s[1]), fmaxf(s[2], s[3])), sm1);
  float e[4], ls = 0.f;
#pragma unroll
  for (int i = 0; i < 4; i++) { e[i] = __expf(s[i] - m); ls += e[i]; }
  float sum = block_sum(ls, sm2);
  float inv = 1.f / sum;
  float4 ps = *(const float4*)&pos[(size_t)q * N + tid * 4];
  float psv[4] = {ps.x, ps.y, ps.z, ps.w};
  float a[4], ent = 0.f;
#pragma unroll
  for (int i = 0; i < 4; i++) {
    float patch = e[i] * inv;
    a[i] = (1.f - g) * patch + g * psv[i];
    ent += -a[i] * __logf(a[i] + 1e-8f);
  }
  float E = block_sum(ent, sm3);
  bf16x4 o;
  o.x = (bf16_t)a[0]; o.y = (bf16_t)a[1]; o.z = (bf16_t)a[2]; o.w = (bf16_t)a[3];
  *(bf16x4*)&((bf16_t*)Srow)[tid * 4] = o; // in place over own 8 bytes
  // hmap = 2*(1 - sigmoid(z)) = 2/(1+exp(z)),  z = temp*E
  if (tid == 0) hmap[row] = 2.f / (1.f + __expf(temp[0] * E));
}

// ---------------- NT GEMM: 256 x (NJ*64) tile, BK=64, 8 waves, 8-phase counted-vmcnt
// C[M][Nc] = A[M][K] * B[Nc][K]^T * scale.   REQUIRES: K % 128 == 0 (nk even).
// NJ = N-frags per wave: NJ=4 -> BN=256, NJ=3 -> BN=192 (fills 256-CU grids for N=768).
// 8 waves in 2(M)x4(N); each wave owns 128 x NJ*16 (acc[8][NJ] of 16x16 frags).
// LDS ring: 2 K-tile buffers x (A 256x64 + B BN x 64) bf16.
// Staging granularity: 8 KB groups (64 rows x 64 cols bf16 = 512 thr x 16 B).
// Iteration i computes K-tiles t0=2i (buf0, q0-3) and t1=2i+1 (buf1, q4-7).
// Stage schedule (stage only after the staged region's last read has passed a barrier):
//   q0: A(t1) g0,g1   q1: A(t1) g2,g3     [A-buf1 last read: prev iter q7]
//   q2: B(t0+2) g0,g1 q3: B(t0+2) rest + vmcnt(NJ)  [B-buf0 last read q0; A(t1),B(t1) landed]
//   q4: A(t0+2) g0,g1 q5: A(t0+2) g2,g3   [A-buf0 last read q3]
//   q6: B(t1+2) g0,g1 q7: B(t1+2) rest + vmcnt(NJ)  [B-buf1 last read q4; A,B(t0+2) landed]
// Tail (pf=false): vmcnt(0) at q3; no stages after. Prologue stages A(0),B(0),B(1): vmcnt(NJ).
// Raw s_barrier only (no compiler vmcnt(0)). Per-phase:
// {B-frags(q0/q4), A-frags, stage, [vmcnt], bar, setprio, 2*NJ*2 MFMA, setprio, bar}.
//
// T2 LDS slot-XOR swizzle (rule #21: linear DMA dest + pre-swizzled SOURCE + swz READ):
// physical 16B-slot = logical slot ^ (row&7); staging thread tid loads global slot
// (tid&7)^((tid>>3)&7); frag reads XOR byte col with (lr&7)*16. All row offsets are
// ==0 mod 8 so the involution is consistent end-to-end.
//
// swz: 0 = none; 1 = batch-grouping (Gz%8==0): XCD x owns batches [x*Gz/8,(x+1)*Gz/8);
//      2 = by-grouping (Gz==1, Gy%8==0): XCD x owns by in [x*Gy/8,(x+1)*Gy/8) -> A-stripe
//          L2 reuse (fixes 2x A overfetch when Gx blocks share A rows).
template <typename OutT, int NJ>
__global__ __launch_bounds__(512, 1) void gemm_nt_8p(const bf16_t* __restrict__ A, int lda, long long sA,
                                                     const bf16_t* __restrict__ Bm, int ldb, long long sB,
                                                     OutT* __restrict__ C, int ldc, long long sC,
                                                     int K, float scale, int swz) {
  constexpr int BN = NJ * 64;
  constexpr int BUFSZ = 32768 + NJ * 8192; // A-region + B-region bytes per K-tile buffer
  __shared__ __align__(16) char lds_raw[2 * BUFSZ];

  const int tid = threadIdx.x;
  const int lane = tid & 63, wave = tid >> 6; // 8 waves
  const int wr = wave >> 2, wc = wave & 3;    // 2x4 wave grid, each 128 x NJ*16
  const int quad = lane >> 4, lr = lane & 15;

  int bx = blockIdx.x, by = blockIdx.y, bz = blockIdx.z;
  if (swz == 1) {
    int Gx = gridDim.x, Gy = gridDim.y, Gz = gridDim.z;
    int i = bx + Gx * (by + Gy * bz);
    int xcd = i & 7, slot = i >> 3;
    int T = Gx * Gy;
    int bpx = Gz >> 3; // batches per XCD (Gz=16 -> 2)
    bz = xcd * bpx + slot / T;
    int t = slot % T;
    bx = t % Gx;
    by = t / Gx;
  } else if (swz == 2) {
    int Gx = gridDim.x, Gy = gridDim.y;
    int i = bx + Gx * by;
    int xcd = i & 7, slot = i >> 3;
    int ypx = Gy >> 3; // by-stripes per XCD
    by = xcd * ypx + slot / Gx;
    bx = slot % Gx;
  }
  const int tileN = bx * BN, tileM = by * 256;
  A += (long long)bz * sA + (long long)tileM * lda;
  Bm += (long long)bz * sB + (long long)tileN * ldb;
  C += (long long)bz * sC;

  // per-thread staging source (pre-swizzled column): thread tid covers
  // row (tid>>3)+g*64, PHYSICAL slot tid&7 -> GLOBAL slot (tid&7)^((tid>>3)&7)
  const int scol = (((tid & 7) ^ ((tid >> 3) & 7)) * 8);
  const bf16_t* a_src = A + (long long)(tid >> 3) * lda + scol;
  const bf16_t* b_src = Bm + (long long)(tid >> 3) * ldb + scol;

  // LDS dest: linear, wave-uniform base + lane*16 (required by global_load_lds)
  auto STAGE_A = [&](int t, int h) { // h = half (2 groups of 64 rows)
    char* base = lds_raw + (t & 1) * BUFSZ + h * 16384 + wave * 1024;
    const bf16_t* g = a_src + (long long)(h * 128) * lda + t * 64;
    ASYNC_COPY16(g, base);
    ASYNC_COPY16(g + (long long)64 * lda, base + 8192);
  };
  auto STAGE_B_G = [&](int t, int g) { // one 64-row group
    char* base = lds_raw + (t & 1) * BUFSZ + 32768 + g * 8192 + wave * 1024;
    const bf16_t* gp = b_src + (long long)(g * 64) * ldb + t * 64;
    ASYNC_COPY16(gp, base);
  };
  auto WAIT_NJ = [&]() {
    if constexpr (NJ == 4) asm volatile("s_waitcnt vmcnt(4)" ::: "memory");
    else                   asm volatile("s_waitcnt vmcnt(3)" ::: "memory");
  };

  f32x4 acc[8][NJ];
#pragma unroll
  for (int i = 0; i < 8; i++)
#pragma unroll
    for (int j = 0; j < NJ; j++) acc[i][j] = (f32x4){0.f, 0.f, 0.f, 0.f};

  const int nk = K >> 6;     // K-tiles (even: K=768 -> 12, K=1024 -> 16)
  const int niter = nk >> 1;

  // prologue: stage tile0 fully + B(1); A(1) is staged in-loop at q0/q1.
  STAGE_A(0, 0); STAGE_A(0, 1);
#pragma unroll
  for (int g = 0; g < NJ; g++) STAGE_B_G(0, g);
#pragma unroll
  for (int g = 0; g < NJ; g++) STAGE_B_G(1, g);
  WAIT_NJ();
  __builtin_amdgcn_s_barrier();

  for (int it = 0; it < niter; ++it) {
    const int t1 = 2 * it + 1;
    const bool pf = (t1 + 1) < nk; // next K-tile pair exists
    bf16x8 bfr[NJ][2];             // B frags: loaded at q0/q4, held 4 phases
#pragma unroll
    for (int q = 0; q < 8; ++q) {
      const int hb = q >> 2, qq = q & 3;
      const bf16_t* As = (const bf16_t*)(lds_raw + hb * BUFSZ + wr * 16384);
      const bf16_t* Bs = (const bf16_t*)(lds_raw + hb * BUFSZ + 32768);
      if (qq == 0) {
#pragma unroll
        for (int nj = 0; nj < NJ; ++nj)
#pragma unroll
          for (int kk = 0; kk < 2; ++kk)
            bfr[nj][kk] = *(const bf16x8*)&Bs[(wc * (NJ * 16) + nj * 16 + lr) * 64 +
                                              ((kk * 32 + quad * 8) ^ ((lr & 7) * 8))];
      }
      bf16x8 af[2][2];
#pragma unroll
      for (int s = 0; s < 2; ++s)
#pragma unroll
        for (int kk = 0; kk < 2; ++kk)
          af[s][kk] = *(const bf16x8*)&As[((qq * 2 + s) * 16 + lr) * 64 +
                                          ((kk * 32 + quad * 8) ^ ((lr & 7) * 8))];
      // stage: see schedule in header comment
      if (q == 0) {
        STAGE_A(t1, 0);
      } else if (q == 1) {
        STAGE_A(t1, 1);
      } else if (q == 2) {
        if (pf) { STAGE_B_G(t1 + 1, 0); STAGE_B_G(t1 + 1, 1); }
      } else if (q == 3) {
        if (pf) {
          STAGE_B_G(t1 + 1, 2);
          if constexpr (NJ == 4) STAGE_B_G(t1 + 1, 3);
          WAIT_NJ();   // A(t1),B(t1) landed
        } else {
          asm volatile("s_waitcnt vmcnt(0)" ::: "memory"); // tail: drain (A(t1) landed)
        }
      } else if (q == 4) {
        if (pf) STAGE_A(t1 + 1, 0);
      } else if (q == 5) {
        if (pf) STAGE_A(t1 + 1, 1);
      } else if (q == 6) {
        if (pf) { STAGE_B_G(t1 + 2, 0); STAGE_B_G(t1 + 2, 1); }
      } else { // q == 7
        if (pf) {
          STAGE_B_G(t1 + 2, 2);
          if constexpr (NJ == 4) STAGE_B_G(t1 + 2, 3);
          WAIT_NJ();   // A(t0+2),B(t0+2) landed
        }
      }
      __builtin_amdgcn_s_barrier();
      __builtin_amdgcn_s_setprio(1);
#pragma unroll
      for (int s = 0; s < 2; ++s)
#pragma unroll
        for (int nj = 0; nj < NJ; ++nj)
#pragma unroll
          for (int kk = 0; kk < 2; ++kk)
            acc[qq * 2 + s][nj] =
                __builtin_amdgcn_mfma_f32_16x16x32_bf16(af[s][kk], bfr[nj][kk], acc[qq * 2 + s][nj], 0, 0, 0);
      __builtin_amdgcn_s_setprio(0);
      __builtin_amdgcn_s_barrier();
    }
  }
  __syncthreads(); // full drain before LDS repurpose (epilogue)

  // ---- epilogue: per-wave repack, 16-row chunks (per-wave private 16x68 f32) ----
  float* epi = (float*)lds_raw + wave * (16 * 68);
#pragma unroll
  for (int mi = 0; mi < 8; ++mi) {
#pragma unroll
    for (int nj = 0; nj < NJ; ++nj)
#pragma unroll
      for (int r = 0; r < 4; ++r)
        epi[(quad * 4 + r) * 68 + nj * 16 + lr] = acc[mi][nj][r] * scale;
    if constexpr (NJ == 4) {
      if constexpr (sizeof(OutT) == 4) {
#pragma unroll
        for (int seg = 0; seg < 4; seg++) {
          int lrow = seg * 4 + (lane >> 4);
          f32x4 v = *(const f32x4*)&epi[lrow * 68 + (lane & 15) * 4];
          long long grow = tileM + wr * 128 + mi * 16 + lrow;
          int gcol = tileN + wc * 64 + (lane & 15) * 4;
          *(f32x4*)&C[grow * ldc + gcol] = v;
        }
      } else {
#pragma unroll
        for (int seg = 0; seg < 2; seg++) {
          int lrow = seg * 8 + (lane >> 3);
          const float* p = &epi[lrow * 68 + (lane & 7) * 8];
          f32x4 v0 = *(const f32x4*)&p[0];
          f32x4 v1 = *(const f32x4*)&p[4];
          __align__(16) OutT o8[8];
#pragma unroll
          for (int j = 0; j < 4; j++) { o8[j] = (OutT)v0[j]; o8[j + 4] = (OutT)v1[j]; }
          long long grow = tileM + wr * 128 + mi * 16 + lrow;
          int gcol = tileN + wc * 64 + (lane & 7) * 8;
          *(f32x4*)&C[grow * ldc + gcol] = *(const f32x4*)o8;
        }
      }
    } else { // NJ == 3: wave owns 48 cols; 48 active lanes per pass
      if constexpr (sizeof(OutT) == 4) {
#pragma unroll
        for (int seg = 0; seg < 4; seg++) {
          if (lane < 48) {
            int lrow = seg * 4 + lane / 12;
            int c4 = (lane % 12) * 4;
            f32x4 v = *(const f32x4*)&epi[lrow * 68 + c4];
            long long grow = tileM + wr * 128 + mi * 16 + lrow;
            int gcol = tileN + wc * 48 + c4;
            *(f32x4*)&C[grow * ldc + gcol] = v;
          }
        }
      } else {
#pragma unroll
        for (int seg = 0; seg < 2; seg++) {
          if (lane < 48) {
            int lrow = seg * 8 + lane / 6;
            int c8 = (lane % 6) * 8;
            const float* p = &epi[lrow * 68 + c8];
            f32x4 v0 = *(const f32x4*)&p[0];
            f32x4 v1 = *(const f32x4*)&p[4];
            __align__(16) OutT o8[8];
#pragma unroll
            for (int j = 0; j < 4; j++) { o8[j] = (OutT)v0[j]; o8[j + 4] = (OutT)v1[j]; }
            long long grow = tileM + wr * 128 + mi * 16 + lrow;
            int gcol = tileN + wc * 48 + c8;
            *(f32x4*)&C[grow * ldc + gcol] = *(const f32x4*)o8;
          }
        }
      }
    }
  }
}

extern "C" void kernel_launch(void* const* d_in, const int* in_sizes, int n_in,
                              void* d_out, int out_size, void* d_ws, size_t ws_size,
                              hipStream_t stream) {
  const float* x = (const float*)d_in[0];      // [B][N][D]
  const float* y = (const float*)d_in[1];      // [B][N][D]
  const float* coords = (const float*)d_in[2]; // [N][N][6]
  const float* W = (const float*)d_in[3];      // [D][D]
  const float* pemb = (const float*)d_in[4];   // [N][6]
  const float* gating = (const float*)d_in[5];
  const float* temp = (const float*)d_in[6];
  float* out = (float*)d_out;
  float* hmap = out + (size_t)B * N * D;

  char* ws = (char*)d_ws;
  bf16_t* xb = (bf16_t*)(ws + 0);          // 24 MB
  bf16_t* yb = (bf16_t*)(ws + 25165824);   // 24 MB
  bf16_t* yT = (bf16_t*)(ws + 50331648);   // 24 MB
  bf16_t* Wb = (bf16_t*)(ws + 75497472);   // 1.125 MB
  bf16_t* kb = (bf16_t*)(ws + 76677120);   // 24 MB
  float* pos = (float*)(ws + 101842944);   // 4 MB
  _Float16* S = (_Float16*)(ws + 106037248); // 32 MB f16 scores (attn bf16 in place)

  const int BND = B * N * D; // 12582912

  cast_f32_bf16_4<<<BND / 4 / 256, 256, 0, stream>>>((const float4*)x, (bf16x4*)xb, BND / 4);
  cast_f32_bf16_4<<<(D * D / 4 + 255) / 256, 256, 0, stream>>>((const float4*)W, (bf16x4*)Wb, D * D / 4);
  cast_transpose_y<<<dim3(D / 64, N / 64, B), 256, 0, stream>>>(y, yb, yT);
  pos_softmax_k<<<N, 256, 0, stream>>>(coords, pemb, pos);

  // K1: kb[16384][768] = yb * Wb^T   (M=16384, N=768, K=768) -> BN=192, 4x64 = 256 blocks
  // swz=2: XCD-group the 8-by stripes (A-rows 3 MB/XCD L2-resident; fixes 2x A overfetch)
  gemm_nt_8p<bf16_t, 3><<<dim3(D / 192, (B * N) / 256, 1), 512, 0, stream>>>(
      yb, D, 0LL, Wb, D, 0LL, kb, D, 0LL, D, 1.0f, 2);

  // K3: S[b][n][m] = SCALE * x[b] * k[b]^T  (M=1024, N=1024, K=768), f16 out -> 256 blocks
  gemm_nt_8p<_Float16, 4><<<dim3(N / 256, N / 256, B), 512, 0, stream>>>(
      xb, D, (long long)N * D, kb, D, (long long)N * D, S, N, (long long)N * N, D, SCALE, 1);

  // K4: softmax + gate + entropy; reads f16 scores, writes attn bf16 in place
  attn_entropy_k<<<B * N, 256, 0, stream>>>(S, pos, gating, temp, hmap);

  // K5: out[b][n][d] = attn[b] * y[b]   (M=1024, N=768, K=1024) -> BN=192, 4x4x16 = 256 blocks
  gemm_nt_8p<float, 3><<<dim3(D / 192, N / 256, B), 512, 0, stream>>>(
      (const bf16_t*)S, N, (long long)N * N, yT, N, (long long)N * D, out, D, (long long)N * D, N, 1.0f, 1);
}